// Round 16
// baseline (693.944 us; speedup 1.0000x reference)
//
#include <hip/hip_runtime.h>
#include <stdint.h>

#define T_DIM 512
#define B_DIM 256
#define OBS_DIM 128
#define H_DIM 256
#define TB (T_DIM * B_DIM)
#define NSLOT 4096

typedef _Float16 f16;
typedef __attribute__((ext_vector_type(8))) _Float16 f16x8;
typedef __attribute__((ext_vector_type(4))) float f32x4;

union H2U { f16 h[2]; uint32_t u; };

__device__ __forceinline__ f32x4 fz4() { f32x4 v; v[0]=0.f; v[1]=0.f; v[2]=0.f; v[3]=0.f; return v; }
__device__ __forceinline__ float sigm(float x) {
  float e = __expf(-x);
  return __builtin_amdgcn_rcpf(1.f + e);
}
__device__ __forceinline__ float tanh_f(float x) {
  float e = __expf(-2.f * x);
  return (1.f - e) * __builtin_amdgcn_rcpf(1.f + e);
}

// ---------------------------------------------------------------------------
// K0: weights -> f16. encW 32768 | Wih 196608 | head 8192 (rows0-15 pol,16 val)
// ---------------------------------------------------------------------------
__global__ void k_prep(const float* __restrict__ encW, const float* __restrict__ Wih,
                       const float* __restrict__ polW, const float* __restrict__ valW,
                       f16* __restrict__ encW_h, f16* __restrict__ Wih_h,
                       f16* __restrict__ headW_h) {
  int e = blockIdx.x * 256 + threadIdx.x;
  if (e < 32768) { encW_h[e] = (f16)encW[e]; return; }
  e -= 32768;
  if (e < 196608) { Wih_h[e] = (f16)Wih[e]; return; }
  e -= 196608;
  if (e < 8192) {
    int r = e >> 8, c = e & 255;
    float v = (r < 16) ? polW[r * 256 + c] : (r == 16 ? valW[c] : 0.f);
    headW_h[e] = (f16)v;
  }
}

// ---------------------------------------------------------------------------
// K_sched v2 (unchanged, validated): descending-length sorted seg[].
// ---------------------------------------------------------------------------
__global__ __launch_bounds__(1024) void k_sched(const float* __restrict__ done,
                                                uint32_t* __restrict__ seg,
                                                uint32_t* __restrict__ meta) {
  __shared__ uint32_t sm[256][16];
  __shared__ uint32_t hist[513];
  __shared__ uint32_t offD[513];
  __shared__ uint32_t cnt2[513];
  const int tid = threadIdx.x;
  const int b = tid & 255, c = tid >> 8;

  {
    uint32_t wloc[4] = {0u, 0u, 0u, 0u};
    const int tbase = c * 128;
#pragma unroll 16
    for (int i = 0; i < 128; i++) {
      const int t = tbase + i;
      const float d = (t < 511) ? done[(size_t)t * B_DIM + b] : 0.f;
      wloc[i >> 5] |= (d != 0.f ? 1u : 0u) << (i & 31);
    }
#pragma unroll
    for (int j = 0; j < 4; j++) sm[b][c * 4 + j] = wloc[j];
  }
  for (int i = tid; i < 513; i += 1024) { hist[i] = 0u; cnt2[i] = 0u; }
  __syncthreads();

  if (tid < 256) {
    int t0 = 0;
#pragma unroll
    for (int wdi = 0; wdi < 16; wdi++) {
      uint32_t m = sm[tid][wdi];
      while (m) {
        const int bit = __ffs(m) - 1;
        m &= m - 1;
        const int t = wdi * 32 + bit + 1;
        atomicAdd(&hist[t - t0], 1u);
        t0 = t;
      }
    }
    atomicAdd(&hist[T_DIM - t0], 1u);
  }
  __syncthreads();
  if (tid == 0) {
    uint32_t run = 0;
#pragma unroll 8
    for (int L = 512; L >= 1; L--) { offD[L] = run; run += hist[L]; }
    meta[0] = run;
  }
  __syncthreads();
  if (tid < 256) {
    int t0 = 0;
    const uint32_t bb = (uint32_t)tid << 19;
#pragma unroll
    for (int wdi = 0; wdi < 16; wdi++) {
      uint32_t m = sm[tid][wdi];
      while (m) {
        const int bit = __ffs(m) - 1;
        m &= m - 1;
        const int t = wdi * 32 + bit + 1;
        const uint32_t len = (uint32_t)(t - t0);
        const uint32_t p = offD[len] + atomicAdd(&cnt2[len], 1u);
        seg[p] = bb | ((uint32_t)t0 << 10) | len;
        t0 = t;
      }
    }
    const uint32_t len = (uint32_t)(T_DIM - t0);
    const uint32_t p = offD[len] + atomicAdd(&cnt2[len], 1u);
    seg[p] = bb | ((uint32_t)t0 << 10) | len;
  }
}

// ---------------------------------------------------------------------------
// K1: FUSED encoder + gate GEMM (unchanged, passing).
// ---------------------------------------------------------------------------
__global__ __launch_bounds__(512) void k_encgi(const float* __restrict__ obs,
                                               const f16* __restrict__ encW_h,
                                               const float* __restrict__ enc_b,
                                               const f16* __restrict__ Wih_h,
                                               const float* __restrict__ b_ih,
                                               const float* __restrict__ b_hh,
                                               uint32_t* __restrict__ gi_rz,
                                               f16* __restrict__ xgi) {
  __shared__ __align__(16) char smem[132096];
  f16* xl = (f16*)smem;
  char* r2 = smem + 33792;
  const int tid = threadIdx.x, lane = tid & 63, w = tid >> 6;
  const int m0 = blockIdx.x * 64;
  const int mstrip = w >> 1, ch = w & 1;

#pragma unroll
  for (int i = 0; i < 4; i++) {
    int c = tid + i * 512;
    int r = c >> 5, kk = (c & 31) * 4;
    float4 v = *(const float4*)(obs + (size_t)(m0 + r) * OBS_DIM + kk);
    H2U a, b;
    a.h[0] = (f16)v.x; a.h[1] = (f16)v.y; b.h[0] = (f16)v.z; b.h[1] = (f16)v.w;
    uint32_t off = ((uint32_t)(r * 256 + kk * 2)) ^ (((uint32_t)(r & 7)) << 4);
    uint2 p; p.x = a.u; p.y = b.u;
    *(uint2*)(r2 + off) = p;
  }
#pragma unroll
  for (int i = 0; i < 8; i++) {
    int c = tid + i * 512;
    int r = c >> 4, kk = (c & 15) * 8;
    f16x8 v = *(const f16x8*)(encW_h + (size_t)r * OBS_DIM + kk);
    uint32_t off = ((uint32_t)(r * 256 + kk * 2)) ^ (((uint32_t)(r & 7)) << 4);
    *(f16x8*)(r2 + 16384 + off) = v;
  }
  __syncthreads();
  {
    f32x4 acc[8];
#pragma unroll
    for (int i = 0; i < 8; i++) acc[i] = fz4();
#pragma unroll
    for (int ks = 0; ks < 4; ks++) {
      const int ar = mstrip * 16 + (lane & 15);
      const int kofs = (ks * 32 + ((lane >> 4) << 3)) * 2;
      uint32_t aoff = ((uint32_t)(ar * 256 + kofs)) ^ (((uint32_t)(ar & 7)) << 4);
      f16x8 af = *(const f16x8*)(r2 + aoff);
#pragma unroll
      for (int i = 0; i < 8; i++) {
        const int br = ch * 128 + i * 16 + (lane & 15);
        uint32_t boff = ((uint32_t)(br * 256 + kofs)) ^ (((uint32_t)(br & 7)) << 4);
        f16x8 bfr = *(const f16x8*)(r2 + 16384 + boff);
        acc[i] = __builtin_amdgcn_mfma_f32_16x16x32_f16(af, bfr, acc[i], 0, 0, 0);
      }
    }
#pragma unroll
    for (int i = 0; i < 8; i++) {
      const int col = ch * 128 + i * 16 + (lane & 15);
      const float bb = enc_b[col];
#pragma unroll
      for (int r = 0; r < 4; r++) {
        const int lr = mstrip * 16 + ((lane >> 4) << 2) + r;
        xl[lr * 264 + col] = (f16)tanh_f(acc[i][r] + bb);
      }
    }
  }
  __syncthreads();

  f32x4 acc[3][8];
#pragma unroll
  for (int g = 0; g < 3; g++)
#pragma unroll
    for (int j = 0; j < 8; j++) acc[g][j] = fz4();

  for (int kc = 0; kc < 4; kc++) {
    if (kc) __syncthreads();
#pragma unroll
    for (int i = 0; i < 12; i++) {
      int c = tid + i * 512;
      int r = c >> 3, kk = (c & 7) * 8;
      f16x8 v = *(const f16x8*)(Wih_h + (size_t)r * H_DIM + kc * 64 + kk);
      uint32_t off = ((uint32_t)(r * 128 + kk * 2)) ^ (((uint32_t)(r & 7)) << 4);
      *(f16x8*)(r2 + off) = v;
    }
    __syncthreads();
#pragma unroll
    for (int ks = 0; ks < 2; ks++) {
      const int ar = mstrip * 16 + (lane & 15);
      const int kg = kc * 64 + ks * 32 + ((lane >> 4) << 3);
      f16x8 af = *(const f16x8*)&xl[ar * 264 + kg];
      const int kofs = (ks * 32 + ((lane >> 4) << 3)) * 2;
#pragma unroll
      for (int g = 0; g < 3; g++)
#pragma unroll
        for (int j = 0; j < 8; j++) {
          const int br = g * 256 + ch * 128 + j * 16 + (lane & 15);
          uint32_t boff = ((uint32_t)(br * 128 + kofs)) ^ (((uint32_t)(br & 7)) << 4);
          f16x8 bfr = *(const f16x8*)(r2 + boff);
          acc[g][j] = __builtin_amdgcn_mfma_f32_16x16x32_f16(af, bfr, acc[g][j], 0, 0, 0);
        }
    }
  }
#pragma unroll
  for (int j = 0; j < 8; j++) {
    const int c = ch * 128 + j * 16 + (lane & 15);
    const float bbr = b_ih[c] + b_hh[c];
    const float bbz = b_ih[256 + c] + b_hh[256 + c];
    const float bbn = b_ih[512 + c];
#pragma unroll
    for (int r = 0; r < 4; r++) {
      const size_t tb = (size_t)(m0 + mstrip * 16 + ((lane >> 4) << 2) + r);
      H2U u;
      u.h[0] = (f16)(acc[0][j][r] + bbr);
      u.h[1] = (f16)(acc[1][j][r] + bbz);
      gi_rz[tb * 256 + c] = u.u;
      xgi[tb * 256 + c] = (f16)(acc[2][j][r] + bbn);
    }
  }
}

// ---------------------------------------------------------------------------
// K3: GRU scan v13 = r15 + BLOCK-DEAD LOAD-CLAUSE SKIP. With the permuted
// striped deal, phase-B block r (consecutive sorted ranks 4r..4r+3) goes
// fully execz-dead in order r=3,2,1,0; guarding each r's gi prefetch clause
// on stn[r] now skips whole clauses (loads + addr VALU) for dead blocks.
// Everything else identical to r15 (validated, absmax-exact).
// ---------------------------------------------------------------------------
__global__ __launch_bounds__(512, 1) void k_scan(const float* __restrict__ Whh,
                                                 const float* __restrict__ b_hh,
                                                 const uint32_t* __restrict__ seg,
                                                 const uint32_t* __restrict__ meta,
                                                 const uint32_t* __restrict__ gi_rz,
                                                 f16* xgi) {
  __shared__ f16 h_l[2][16][264];
  __shared__ f16 wb_l[8 * 12 * 64 * 8];
  __shared__ uint32_t st_l[3][16];
  __shared__ uint32_t vmax_l;
  const int tid = threadIdx.x, lane = tid & 63, w = tid >> 6;
  const uint32_t nseg = meta[0];

  if (tid == 0) vmax_l = 0;
  for (int i = tid; i < 2 * 16 * 264; i += 512) ((f16*)h_l)[i] = (f16)0.f;
  __syncthreads();

  f16x8 wf[6][6];
#pragma unroll
  for (int g = 0; g < 3; g++) {
#pragma unroll
    for (int hh = 0; hh < 2; hh++) {
      const int i6 = g * 2 + hh;
      const int rowW = g * 256 + w * 32 + hh * 16 + (lane & 15);
      const float* wrow = Whh + (size_t)rowW * H_DIM;
#pragma unroll
      for (int ks = 0; ks < 8; ks++) {
        const int k0 = ks * 32 + ((lane >> 4) << 3);
        float4 a = *(const float4*)(wrow + k0);
        float4 b = *(const float4*)(wrow + k0 + 4);
        f16x8 f;
        f[0] = (f16)a.x; f[1] = (f16)a.y; f[2] = (f16)a.z; f[3] = (f16)a.w;
        f[4] = (f16)b.x; f[5] = (f16)b.y; f[6] = (f16)b.z; f[7] = (f16)b.w;
        if (ks < 6) wf[i6][ks] = f;
        else *(f16x8*)&wb_l[((w * 12 + i6 * 2 + (ks - 6)) * 64 + lane) * 8] = f;
      }
    }
  }
  f32x4 zs = fz4();
  f32x4 ns0, ns1;
  {
    const float bv0 = b_hh[512 + w * 32 + (lane & 15)];
    const float bv1 = b_hh[512 + w * 32 + 16 + (lane & 15)];
    ns0[0] = bv0; ns0[1] = bv0; ns0[2] = bv0; ns0[3] = bv0;
    ns1[0] = bv1; ns1[1] = bv1; ns1[2] = bv1; ns1[3] = bv1;
  }

  // bookkeeping (threads 0-15 own row tid): PERMUTED-STRIPED sorted positions.
  uint32_t rt = 0, rb = 0, rrem = 0, rnextidx = 0, rnextval = 0;
  bool rnextok = false, rfresh = false;
  if (tid < 16) {
    const uint32_t rank = (uint32_t)((tid & 3) * 4 + (tid >> 2));
    const uint32_t base = rank * 256u + (uint32_t)blockIdx.x;
    uint32_t tot = 0;
#pragma unroll 8
    for (uint32_t k = 0; k < 32; k++) {
      const uint32_t idx = base + k * NSLOT;
      const uint32_t vv = (idx < nseg) ? seg[idx] : 0u;
      tot += vv & 1023u;
    }
    rnextidx = base; rnextok = base < nseg;
    if (rnextok) rnextval = seg[base];
    if (rnextok) {
      rb = rnextval >> 19; rt = (rnextval >> 10) & 511u; rrem = rnextval & 1023u;
      rfresh = true;
      rnextidx += NSLOT; rnextok = rnextidx < nseg;
      if (rnextok) rnextval = seg[rnextidx];
    }
    atomicMax(&vmax_l, tot);
  }
  auto emit = [&]() -> uint32_t {
    uint32_t stv = 0;
    if (rrem > 0) {
      stv = 0x80000000u | (rfresh ? 0x40000000u : 0u) | (rt * 256u + rb);
      rfresh = false; rt++; rrem--;
      if (rrem == 0 && rnextok) {
        rb = rnextval >> 19; rt = (rnextval >> 10) & 511u; rrem = rnextval & 1023u;
        rfresh = true;
        rnextidx += NSLOT; rnextok = rnextidx < nseg;
        if (rnextok) rnextval = seg[rnextidx];
      }
    }
    return stv;
  };
  if (tid < 16) { st_l[0][tid] = emit(); st_l[1][tid] = emit(); }
  __syncthreads();
  const uint32_t vmax = vmax_l;

  const int l = lane & 15;
  const int g4 = (lane >> 4) << 2;
  const int colA = w * 32 + l, colB = colA + 16;
  const f16* hrd0 = &h_l[0][l][(lane >> 4) << 3];
  const f16* wrd = &wb_l[(w * 12 * 64 + lane) * 8];

  // bootstrap: current state + guarded gi load for v=0
  uint32_t stcur[4];
#pragma unroll
  for (int r = 0; r < 4; r++) stcur[r] = st_l[0][g4 + r];
  uint32_t rzC[8] = {0u,0u,0u,0u,0u,0u,0u,0u};
  f16 gnC[8] = {};
#pragma unroll
  for (int r = 0; r < 4; r++) {
    if (stcur[r] & 0x80000000u) {
      uint32_t a0 = (stcur[r] & 0x1FFFFu) * 256u + colA;
      rzC[r * 2] = gi_rz[a0]; rzC[r * 2 + 1] = gi_rz[a0 + 16];
      gnC[r * 2] = xgi[a0];   gnC[r * 2 + 1] = xgi[a0 + 16];
    }
  }
  float hp[4][2];
#pragma unroll
  for (int r = 0; r < 4; r++) { hp[r][0] = 0.f; hp[r][1] = 0.f; }

  int hc = 0, i0 = 0, i1 = 1, i2 = 2;
  for (uint32_t v = 0; v < vmax; ++v) {
    // state for v+1 + gi prefetch clause, SKIPPED per-r once block r is dead
    uint32_t stn[4];
#pragma unroll
    for (int r = 0; r < 4; r++) stn[r] = st_l[i1][g4 + r];
    uint32_t rzN[8] = {0u,0u,0u,0u,0u,0u,0u,0u};
    f16 gnN[8] = {};
#pragma unroll
    for (int r = 0; r < 4; r++) {
      if (stn[r] & 0x80000000u) {
        uint32_t a0 = (stn[r] & 0x1FFFFu) * 256u + colA;
        rzN[r * 2] = gi_rz[a0]; rzN[r * 2 + 1] = gi_rz[a0 + 16];
        gnN[r * 2] = xgi[a0];   gnN[r * 2 + 1] = xgi[a0 + 16];
      }
    }
    if (tid < 16) st_l[i2][tid] = emit();

    // phase A: gh = h @ W_hh^T (48 MFMA)
    const f16* hrd = hrd0 + hc * (16 * 264);
    f32x4 acc[6];
    __builtin_amdgcn_s_setprio(1);
    {
      const f16x8 af0 = *(const f16x8*)&hrd[0];
      acc[0] = __builtin_amdgcn_mfma_f32_16x16x32_f16(af0, wf[0][0], zs, 0, 0, 0);
      acc[1] = __builtin_amdgcn_mfma_f32_16x16x32_f16(af0, wf[1][0], zs, 0, 0, 0);
      acc[2] = __builtin_amdgcn_mfma_f32_16x16x32_f16(af0, wf[2][0], zs, 0, 0, 0);
      acc[3] = __builtin_amdgcn_mfma_f32_16x16x32_f16(af0, wf[3][0], zs, 0, 0, 0);
      acc[4] = __builtin_amdgcn_mfma_f32_16x16x32_f16(af0, wf[4][0], ns0, 0, 0, 0);
      acc[5] = __builtin_amdgcn_mfma_f32_16x16x32_f16(af0, wf[5][0], ns1, 0, 0, 0);
    }
#pragma unroll
    for (int ks = 1; ks < 6; ks++) {
      const f16x8 af = *(const f16x8*)&hrd[ks * 32];
#pragma unroll
      for (int i = 0; i < 6; i++)
        acc[i] = __builtin_amdgcn_mfma_f32_16x16x32_f16(af, wf[i][ks], acc[i], 0, 0, 0);
    }
#pragma unroll
    for (int j = 0; j < 2; j++) {
      const f16x8 af = *(const f16x8*)&hrd[(6 + j) * 32];
#pragma unroll
      for (int i = 0; i < 6; i++) {
        const f16x8 bf = *(const f16x8*)&wrd[(i * 2 + j) * 512];
        acc[i] = __builtin_amdgcn_mfma_f32_16x16x32_f16(af, bf, acc[i], 0, 0, 0);
      }
    }
    __builtin_amdgcn_s_setprio(0);

    // phase B: per-r conditional gate blocks (execz-skipped once block dead)
#pragma unroll
    for (int r = 0; r < 4; r++) {
      const uint32_t sc = stcur[r], sn = stn[r];
      f16 hv0 = (f16)0.f, hv1 = (f16)0.f;
      if (sc & 0x80000000u) {
        const bool freshc = (sc & 0x40000000u) != 0;
        const uint32_t tb = sc & 0x1FFFFu;
        const bool keep = (sn & 0xC0000000u) == 0x80000000u;
        H2U u0; u0.u = rzC[r * 2];
        const float rr0 = sigm((float)u0.h[0] + acc[0][r]);
        const float zz0 = sigm((float)u0.h[1] + acc[2][r]);
        const float nn0 = tanh_f((float)gnC[r * 2] + rr0 * acc[4][r]);
        const float hpv0 = freshc ? 0.f : hp[r][0];
        const float ho0 = nn0 + zz0 * (hpv0 - nn0);
        hp[r][0] = ho0;
        H2U u1; u1.u = rzC[r * 2 + 1];
        const float rr1 = sigm((float)u1.h[0] + acc[1][r]);
        const float zz1 = sigm((float)u1.h[1] + acc[3][r]);
        const float nn1 = tanh_f((float)gnC[r * 2 + 1] + rr1 * acc[5][r]);
        const float hpv1 = freshc ? 0.f : hp[r][1];
        const float ho1 = nn1 + zz1 * (hpv1 - nn1);
        hp[r][1] = ho1;
        xgi[tb * 256u + colA] = (f16)ho0;
        xgi[tb * 256u + colB] = (f16)ho1;
        if (keep) { hv0 = (f16)ho0; hv1 = (f16)ho1; }
      }
      h_l[hc ^ 1][g4 + r][colA] = hv0;
      h_l[hc ^ 1][g4 + r][colB] = hv1;
    }
#pragma unroll
    for (int i = 0; i < 8; i++) { rzC[i] = rzN[i]; gnC[i] = gnN[i]; }
#pragma unroll
    for (int r = 0; r < 4; r++) stcur[r] = stn[r];

    __builtin_amdgcn_sched_barrier(0);
    asm volatile("s_waitcnt lgkmcnt(0)" ::: "memory");
    __builtin_amdgcn_s_barrier();
    __builtin_amdgcn_sched_barrier(0);

    hc ^= 1;
    const int tr = i0; i0 = i1; i1 = i2; i2 = tr;
  }
}

// ---------------------------------------------------------------------------
// K4: heads. M-tile 128, N=32 (16 pol + 1 val + pad), grid 1024, block 512.
// ---------------------------------------------------------------------------
__global__ __launch_bounds__(512) void k_heads(const f16* __restrict__ outs,
                                               const f16* __restrict__ headW_h,
                                               const float* __restrict__ pol_b,
                                               const float* __restrict__ val_b,
                                               float* __restrict__ out) {
  __shared__ f16 lA[128 * 256];
  __shared__ f16 lB[32 * 256];
  const int tid = threadIdx.x, lane = tid & 63, w = tid >> 6;
  const int m0 = blockIdx.x * 128;
#pragma unroll
  for (int i = 0; i < 8; i++) {
    int c = tid + i * 512;
    int r = c >> 5, o = (c & 31) * 8;
    f16x8 v = *(const f16x8*)(outs + (size_t)(m0 + r) * H_DIM + o);
    uint32_t off = ((uint32_t)(r * 512 + o * 2)) ^ (((uint32_t)(r & 7)) << 4);
    *(f16x8*)((char*)lA + off) = v;
  }
#pragma unroll
  for (int i = 0; i < 2; i++) {
    int c = tid + i * 512;
    int r = c >> 5, o = (c & 31) * 8;
    f16x8 v = *(const f16x8*)(headW_h + (size_t)r * H_DIM + o);
    uint32_t off = ((uint32_t)(r * 512 + o * 2)) ^ (((uint32_t)(r & 7)) << 4);
    *(f16x8*)((char*)lB + off) = v;
  }
  __syncthreads();
  f32x4 acc[2];
  acc[0] = fz4(); acc[1] = fz4();
#pragma unroll
  for (int ks = 0; ks < 8; ks++) {
    const int ar = w * 16 + (lane & 15);
    const int kofs = (ks * 32 + ((lane >> 4) << 3)) * 2;
    uint32_t aoff = ((uint32_t)(ar * 512 + kofs)) ^ (((uint32_t)(ar & 7)) << 4);
    f16x8 af = *(const f16x8*)((char*)lA + aoff);
#pragma unroll
    for (int nt = 0; nt < 2; nt++) {
      const int br = nt * 16 + (lane & 15);
      uint32_t boff = ((uint32_t)(br * 512 + kofs)) ^ (((uint32_t)(br & 7)) << 4);
      f16x8 bfr = *(const f16x8*)((char*)lB + boff);
      acc[nt] = __builtin_amdgcn_mfma_f32_16x16x32_f16(af, bfr, acc[nt], 0, 0, 0);
    }
  }
  const int n = lane & 15;
  const float pb = pol_b[n];
  const float vb = val_b[0];
#pragma unroll
  for (int r = 0; r < 4; r++) {
    const int mrow = m0 + w * 16 + ((lane >> 4) << 2) + r;
    out[(size_t)mrow * 16 + n] = acc[0][r] + pb;
    if (n == 0) out[(size_t)TB * 16 + mrow] = acc[1][r] + vb;
  }
}

// ---------------------------------------------------------------------------
// Workspace layout (~193.0 MiB total):
//   [0,128Mi)          gi_rz f16 [TB][256][2] (r,z interleaved; u32 cells)
//   [128Mi,192Mi)      xgi  f16 [TB][256]  (gi_n -> outs, race-free)
//   [192Mi,+464KB)     encW_h | Wih_h | headW_h
//   [+464KB,+976KB)    seg u32[131072] | meta u32[1]
// ---------------------------------------------------------------------------
extern "C" void kernel_launch(void* const* d_in, const int* in_sizes, int n_in,
                              void* d_out, int out_size, void* d_ws, size_t ws_size,
                              hipStream_t stream) {
  (void)in_sizes; (void)n_in; (void)out_size; (void)ws_size;
  const float* obs   = (const float*)d_in[0];
  const float* done  = (const float*)d_in[1];
  const float* encW  = (const float*)d_in[2];
  const float* enc_b = (const float*)d_in[3];
  const float* Wih   = (const float*)d_in[4];
  const float* Whh   = (const float*)d_in[5];
  const float* b_ih  = (const float*)d_in[6];
  const float* b_hh  = (const float*)d_in[7];
  const float* polW  = (const float*)d_in[8];
  const float* pol_b = (const float*)d_in[9];
  const float* valW  = (const float*)d_in[10];
  const float* val_b = (const float*)d_in[11];

  char* ws = (char*)d_ws;
  f16* gi_rz   = (f16*)ws;
  f16* xgi     = (f16*)(ws + (size_t)134217728);
  f16* encW_h  = (f16*)(ws + (size_t)201326592);
  f16* Wih_h   = encW_h + 32768;
  f16* headW_h = Wih_h + 196608;
  uint32_t* seg  = (uint32_t*)(ws + (size_t)201801728);
  uint32_t* meta = (uint32_t*)(ws + (size_t)202326016);
  float* outp  = (float*)d_out;

  k_prep<<<dim3(928), dim3(256), 0, stream>>>(encW, Wih, polW, valW, encW_h, Wih_h, headW_h);
  k_sched<<<dim3(1), dim3(1024), 0, stream>>>(done, seg, meta);
  k_encgi<<<dim3(2048), dim3(512), 0, stream>>>(obs, encW_h, enc_b, Wih_h, b_ih, b_hh,
                                                (uint32_t*)gi_rz, xgi);
  k_scan<<<dim3(256), dim3(512), 0, stream>>>(Whh, b_hh, seg, meta,
                                              (const uint32_t*)gi_rz, xgi);
  k_heads<<<dim3(1024), dim3(512), 0, stream>>>(xgi, headW_h, pol_b, val_b, outp);
}

// Round 17
// 560.157 us; speedup vs baseline: 1.2388x; 1.2388x over previous
//
#include <hip/hip_runtime.h>
#include <stdint.h>

#define T_DIM 512
#define B_DIM 256
#define OBS_DIM 128
#define H_DIM 256
#define TB (T_DIM * B_DIM)
#define NSLOT 4096

typedef _Float16 f16;
typedef __attribute__((ext_vector_type(8))) _Float16 f16x8;
typedef __attribute__((ext_vector_type(4))) float f32x4;

union H2U { f16 h[2]; uint32_t u; };

__device__ __forceinline__ f32x4 fz4() { f32x4 v; v[0]=0.f; v[1]=0.f; v[2]=0.f; v[3]=0.f; return v; }
__device__ __forceinline__ float sigm(float x) {
  float e = __expf(-x);
  return __builtin_amdgcn_rcpf(1.f + e);
}
__device__ __forceinline__ float tanh_f(float x) {
  float e = __expf(-2.f * x);
  return (1.f - e) * __builtin_amdgcn_rcpf(1.f + e);
}

// ---------------------------------------------------------------------------
// K0: weights -> f16. encW 32768 | Wih 196608 | head 8192 (rows0-15 pol,16 val)
// ---------------------------------------------------------------------------
__global__ void k_prep(const float* __restrict__ encW, const float* __restrict__ Wih,
                       const float* __restrict__ polW, const float* __restrict__ valW,
                       f16* __restrict__ encW_h, f16* __restrict__ Wih_h,
                       f16* __restrict__ headW_h) {
  int e = blockIdx.x * 256 + threadIdx.x;
  if (e < 32768) { encW_h[e] = (f16)encW[e]; return; }
  e -= 32768;
  if (e < 196608) { Wih_h[e] = (f16)Wih[e]; return; }
  e -= 196608;
  if (e < 8192) {
    int r = e >> 8, c = e & 255;
    float v = (r < 16) ? polW[r * 256 + c] : (r == 16 ? valW[c] : 0.f);
    headW_h[e] = (f16)v;
  }
}

// ---------------------------------------------------------------------------
// K_sched v2 (validated): descending-length sorted seg[].
// ---------------------------------------------------------------------------
__global__ __launch_bounds__(1024) void k_sched(const float* __restrict__ done,
                                                uint32_t* __restrict__ seg,
                                                uint32_t* __restrict__ meta) {
  __shared__ uint32_t sm[256][16];
  __shared__ uint32_t hist[513];
  __shared__ uint32_t offD[513];
  __shared__ uint32_t cnt2[513];
  const int tid = threadIdx.x;
  const int b = tid & 255, c = tid >> 8;

  {
    uint32_t wloc[4] = {0u, 0u, 0u, 0u};
    const int tbase = c * 128;
#pragma unroll 16
    for (int i = 0; i < 128; i++) {
      const int t = tbase + i;
      const float d = (t < 511) ? done[(size_t)t * B_DIM + b] : 0.f;
      wloc[i >> 5] |= (d != 0.f ? 1u : 0u) << (i & 31);
    }
#pragma unroll
    for (int j = 0; j < 4; j++) sm[b][c * 4 + j] = wloc[j];
  }
  for (int i = tid; i < 513; i += 1024) { hist[i] = 0u; cnt2[i] = 0u; }
  __syncthreads();

  if (tid < 256) {
    int t0 = 0;
#pragma unroll
    for (int wdi = 0; wdi < 16; wdi++) {
      uint32_t m = sm[tid][wdi];
      while (m) {
        const int bit = __ffs(m) - 1;
        m &= m - 1;
        const int t = wdi * 32 + bit + 1;
        atomicAdd(&hist[t - t0], 1u);
        t0 = t;
      }
    }
    atomicAdd(&hist[T_DIM - t0], 1u);
  }
  __syncthreads();
  if (tid == 0) {
    uint32_t run = 0;
#pragma unroll 8
    for (int L = 512; L >= 1; L--) { offD[L] = run; run += hist[L]; }
    meta[0] = run;
  }
  __syncthreads();
  if (tid < 256) {
    int t0 = 0;
    const uint32_t bb = (uint32_t)tid << 19;
#pragma unroll
    for (int wdi = 0; wdi < 16; wdi++) {
      uint32_t m = sm[tid][wdi];
      while (m) {
        const int bit = __ffs(m) - 1;
        m &= m - 1;
        const int t = wdi * 32 + bit + 1;
        const uint32_t len = (uint32_t)(t - t0);
        const uint32_t p = offD[len] + atomicAdd(&cnt2[len], 1u);
        seg[p] = bb | ((uint32_t)t0 << 10) | len;
        t0 = t;
      }
    }
    const uint32_t len = (uint32_t)(T_DIM - t0);
    const uint32_t p = offD[len] + atomicAdd(&cnt2[len], 1u);
    seg[p] = bb | ((uint32_t)t0 << 10) | len;
  }
}

// ---------------------------------------------------------------------------
// K1: FUSED encoder + gate GEMM (validated).
// ---------------------------------------------------------------------------
__global__ __launch_bounds__(512) void k_encgi(const float* __restrict__ obs,
                                               const f16* __restrict__ encW_h,
                                               const float* __restrict__ enc_b,
                                               const f16* __restrict__ Wih_h,
                                               const float* __restrict__ b_ih,
                                               const float* __restrict__ b_hh,
                                               uint32_t* __restrict__ gi_rz,
                                               f16* __restrict__ xgi) {
  __shared__ __align__(16) char smem[132096];
  f16* xl = (f16*)smem;
  char* r2 = smem + 33792;
  const int tid = threadIdx.x, lane = tid & 63, w = tid >> 6;
  const int m0 = blockIdx.x * 64;
  const int mstrip = w >> 1, ch = w & 1;

#pragma unroll
  for (int i = 0; i < 4; i++) {
    int c = tid + i * 512;
    int r = c >> 5, kk = (c & 31) * 4;
    float4 v = *(const float4*)(obs + (size_t)(m0 + r) * OBS_DIM + kk);
    H2U a, b;
    a.h[0] = (f16)v.x; a.h[1] = (f16)v.y; b.h[0] = (f16)v.z; b.h[1] = (f16)v.w;
    uint32_t off = ((uint32_t)(r * 256 + kk * 2)) ^ (((uint32_t)(r & 7)) << 4);
    uint2 p; p.x = a.u; p.y = b.u;
    *(uint2*)(r2 + off) = p;
  }
#pragma unroll
  for (int i = 0; i < 8; i++) {
    int c = tid + i * 512;
    int r = c >> 4, kk = (c & 15) * 8;
    f16x8 v = *(const f16x8*)(encW_h + (size_t)r * OBS_DIM + kk);
    uint32_t off = ((uint32_t)(r * 256 + kk * 2)) ^ (((uint32_t)(r & 7)) << 4);
    *(f16x8*)(r2 + 16384 + off) = v;
  }
  __syncthreads();
  {
    f32x4 acc[8];
#pragma unroll
    for (int i = 0; i < 8; i++) acc[i] = fz4();
#pragma unroll
    for (int ks = 0; ks < 4; ks++) {
      const int ar = mstrip * 16 + (lane & 15);
      const int kofs = (ks * 32 + ((lane >> 4) << 3)) * 2;
      uint32_t aoff = ((uint32_t)(ar * 256 + kofs)) ^ (((uint32_t)(ar & 7)) << 4);
      f16x8 af = *(const f16x8*)(r2 + aoff);
#pragma unroll
      for (int i = 0; i < 8; i++) {
        const int br = ch * 128 + i * 16 + (lane & 15);
        uint32_t boff = ((uint32_t)(br * 256 + kofs)) ^ (((uint32_t)(br & 7)) << 4);
        f16x8 bfr = *(const f16x8*)(r2 + 16384 + boff);
        acc[i] = __builtin_amdgcn_mfma_f32_16x16x32_f16(af, bfr, acc[i], 0, 0, 0);
      }
    }
#pragma unroll
    for (int i = 0; i < 8; i++) {
      const int col = ch * 128 + i * 16 + (lane & 15);
      const float bb = enc_b[col];
#pragma unroll
      for (int r = 0; r < 4; r++) {
        const int lr = mstrip * 16 + ((lane >> 4) << 2) + r;
        xl[lr * 264 + col] = (f16)tanh_f(acc[i][r] + bb);
      }
    }
  }
  __syncthreads();

  f32x4 acc[3][8];
#pragma unroll
  for (int g = 0; g < 3; g++)
#pragma unroll
    for (int j = 0; j < 8; j++) acc[g][j] = fz4();

  for (int kc = 0; kc < 4; kc++) {
    if (kc) __syncthreads();
#pragma unroll
    for (int i = 0; i < 12; i++) {
      int c = tid + i * 512;
      int r = c >> 3, kk = (c & 7) * 8;
      f16x8 v = *(const f16x8*)(Wih_h + (size_t)r * H_DIM + kc * 64 + kk);
      uint32_t off = ((uint32_t)(r * 128 + kk * 2)) ^ (((uint32_t)(r & 7)) << 4);
      *(f16x8*)(r2 + off) = v;
    }
    __syncthreads();
#pragma unroll
    for (int ks = 0; ks < 2; ks++) {
      const int ar = mstrip * 16 + (lane & 15);
      const int kg = kc * 64 + ks * 32 + ((lane >> 4) << 3);
      f16x8 af = *(const f16x8*)&xl[ar * 264 + kg];
      const int kofs = (ks * 32 + ((lane >> 4) << 3)) * 2;
#pragma unroll
      for (int g = 0; g < 3; g++)
#pragma unroll
        for (int j = 0; j < 8; j++) {
          const int br = g * 256 + ch * 128 + j * 16 + (lane & 15);
          uint32_t boff = ((uint32_t)(br * 128 + kofs)) ^ (((uint32_t)(br & 7)) << 4);
          f16x8 bfr = *(const f16x8*)(r2 + boff);
          acc[g][j] = __builtin_amdgcn_mfma_f32_16x16x32_f16(af, bfr, acc[g][j], 0, 0, 0);
        }
    }
  }
#pragma unroll
  for (int j = 0; j < 8; j++) {
    const int c = ch * 128 + j * 16 + (lane & 15);
    const float bbr = b_ih[c] + b_hh[c];
    const float bbz = b_ih[256 + c] + b_hh[256 + c];
    const float bbn = b_ih[512 + c];
#pragma unroll
    for (int r = 0; r < 4; r++) {
      const size_t tb = (size_t)(m0 + mstrip * 16 + ((lane >> 4) << 2) + r);
      H2U u;
      u.h[0] = (f16)(acc[0][j][r] + bbr);
      u.h[1] = (f16)(acc[1][j][r] + bbz);
      gi_rz[tb * 256 + c] = u.u;
      xgi[tb * 256 + c] = (f16)(acc[2][j][r] + bbn);
    }
  }
}

// ---------------------------------------------------------------------------
// K3: GRU scan v12 (r15 artifact, measured optimum). SEGMENT-PARALLEL with
// r13's UNCONDITIONAL clause-batched loads + permuted-striped deal (rank =
// (tid&3)*4 + (tid>>2)) + per-r CONDITIONAL gate blocks (execz-skipped once
// a block's 4 consecutive-rank segments are all dead).
// NOTE (r14/r16 falsifications): do NOT guard the gi load clauses — branchy
// loads defeat clause batching and cost more than the dead loads (L2 hits).
// ---------------------------------------------------------------------------
__global__ __launch_bounds__(512, 1) void k_scan(const float* __restrict__ Whh,
                                                 const float* __restrict__ b_hh,
                                                 const uint32_t* __restrict__ seg,
                                                 const uint32_t* __restrict__ meta,
                                                 const uint32_t* __restrict__ gi_rz,
                                                 f16* xgi) {
  __shared__ f16 h_l[2][16][264];
  __shared__ f16 wb_l[8 * 12 * 64 * 8];
  __shared__ uint32_t st_l[3][16];
  __shared__ uint32_t vmax_l;
  const int tid = threadIdx.x, lane = tid & 63, w = tid >> 6;
  const uint32_t nseg = meta[0];

  if (tid == 0) vmax_l = 0;
  for (int i = tid; i < 2 * 16 * 264; i += 512) ((f16*)h_l)[i] = (f16)0.f;
  __syncthreads();

  f16x8 wf[6][6];
#pragma unroll
  for (int g = 0; g < 3; g++) {
#pragma unroll
    for (int hh = 0; hh < 2; hh++) {
      const int i6 = g * 2 + hh;
      const int rowW = g * 256 + w * 32 + hh * 16 + (lane & 15);
      const float* wrow = Whh + (size_t)rowW * H_DIM;
#pragma unroll
      for (int ks = 0; ks < 8; ks++) {
        const int k0 = ks * 32 + ((lane >> 4) << 3);
        float4 a = *(const float4*)(wrow + k0);
        float4 b = *(const float4*)(wrow + k0 + 4);
        f16x8 f;
        f[0] = (f16)a.x; f[1] = (f16)a.y; f[2] = (f16)a.z; f[3] = (f16)a.w;
        f[4] = (f16)b.x; f[5] = (f16)b.y; f[6] = (f16)b.z; f[7] = (f16)b.w;
        if (ks < 6) wf[i6][ks] = f;
        else *(f16x8*)&wb_l[((w * 12 + i6 * 2 + (ks - 6)) * 64 + lane) * 8] = f;
      }
    }
  }
  f32x4 zs = fz4();
  f32x4 ns0, ns1;
  {
    const float bv0 = b_hh[512 + w * 32 + (lane & 15)];
    const float bv1 = b_hh[512 + w * 32 + 16 + (lane & 15)];
    ns0[0] = bv0; ns0[1] = bv0; ns0[2] = bv0; ns0[3] = bv0;
    ns1[0] = bv1; ns1[1] = bv1; ns1[2] = bv1; ns1[3] = bv1;
  }

  // bookkeeping (threads 0-15 own row tid): PERMUTED-STRIPED sorted positions.
  // rank(row) = (row&3)*4 + (row>>2): block r={rows 4r..4r+3} gets consecutive
  // ranks -> blocks die cleanly in order 3,2,1,0.
  uint32_t rt = 0, rb = 0, rrem = 0, rnextidx = 0, rnextval = 0;
  bool rnextok = false, rfresh = false;
  if (tid < 16) {
    const uint32_t rank = (uint32_t)((tid & 3) * 4 + (tid >> 2));
    const uint32_t base = rank * 256u + (uint32_t)blockIdx.x;
    uint32_t tot = 0;
#pragma unroll 8
    for (uint32_t k = 0; k < 32; k++) {
      const uint32_t idx = base + k * NSLOT;
      const uint32_t vv = (idx < nseg) ? seg[idx] : 0u;
      tot += vv & 1023u;
    }
    rnextidx = base; rnextok = base < nseg;
    if (rnextok) rnextval = seg[base];
    if (rnextok) {
      rb = rnextval >> 19; rt = (rnextval >> 10) & 511u; rrem = rnextval & 1023u;
      rfresh = true;
      rnextidx += NSLOT; rnextok = rnextidx < nseg;
      if (rnextok) rnextval = seg[rnextidx];
    }
    atomicMax(&vmax_l, tot);
  }
  auto emit = [&]() -> uint32_t {
    uint32_t stv = 0;
    if (rrem > 0) {
      stv = 0x80000000u | (rfresh ? 0x40000000u : 0u) | (rt * 256u + rb);
      rfresh = false; rt++; rrem--;
      if (rrem == 0 && rnextok) {
        rb = rnextval >> 19; rt = (rnextval >> 10) & 511u; rrem = rnextval & 1023u;
        rfresh = true;
        rnextidx += NSLOT; rnextok = rnextidx < nseg;
        if (rnextok) rnextval = seg[rnextidx];
      }
    }
    return stv;
  };
  if (tid < 16) { st_l[0][tid] = emit(); st_l[1][tid] = emit(); }
  __syncthreads();
  const uint32_t vmax = vmax_l;

  const int l = lane & 15;
  const int g4 = (lane >> 4) << 2;
  const int colA = w * 32 + l, colB = colA + 16;
  const f16* hrd0 = &h_l[0][l][(lane >> 4) << 3];
  const f16* wrd = &wb_l[(w * 12 * 64 + lane) * 8];

  // bootstrap: current state + unconditional gi load clause for v=0
  uint32_t stcur[4];
#pragma unroll
  for (int r = 0; r < 4; r++) stcur[r] = st_l[0][g4 + r];
  uint32_t rzC[8]; f16 gnC[8];
#pragma unroll
  for (int r = 0; r < 4; r++) {
    uint32_t a0 = (stcur[r] & 0x1FFFFu) * 256u + colA;
    rzC[r * 2] = gi_rz[a0]; rzC[r * 2 + 1] = gi_rz[a0 + 16];
    gnC[r * 2] = xgi[a0];   gnC[r * 2 + 1] = xgi[a0 + 16];
  }
  float hp[4][2];
#pragma unroll
  for (int r = 0; r < 4; r++) { hp[r][0] = 0.f; hp[r][1] = 0.f; }

  int hc = 0, i0 = 0, i1 = 1, i2 = 2;
  for (uint32_t v = 0; v < vmax; ++v) {
    // state for v+1 + UNCONDITIONAL gi prefetch clause
    uint32_t stn[4];
#pragma unroll
    for (int r = 0; r < 4; r++) stn[r] = st_l[i1][g4 + r];
    uint32_t rzN[8]; f16 gnN[8];
#pragma unroll
    for (int r = 0; r < 4; r++) {
      uint32_t a0 = (stn[r] & 0x1FFFFu) * 256u + colA;
      rzN[r * 2] = gi_rz[a0]; rzN[r * 2 + 1] = gi_rz[a0 + 16];
      gnN[r * 2] = xgi[a0];   gnN[r * 2 + 1] = xgi[a0 + 16];
    }
    if (tid < 16) st_l[i2][tid] = emit();

    // phase A: gh = h @ W_hh^T (48 MFMA)
    const f16* hrd = hrd0 + hc * (16 * 264);
    f32x4 acc[6];
    __builtin_amdgcn_s_setprio(1);
    {
      const f16x8 af0 = *(const f16x8*)&hrd[0];
      acc[0] = __builtin_amdgcn_mfma_f32_16x16x32_f16(af0, wf[0][0], zs, 0, 0, 0);
      acc[1] = __builtin_amdgcn_mfma_f32_16x16x32_f16(af0, wf[1][0], zs, 0, 0, 0);
      acc[2] = __builtin_amdgcn_mfma_f32_16x16x32_f16(af0, wf[2][0], zs, 0, 0, 0);
      acc[3] = __builtin_amdgcn_mfma_f32_16x16x32_f16(af0, wf[3][0], zs, 0, 0, 0);
      acc[4] = __builtin_amdgcn_mfma_f32_16x16x32_f16(af0, wf[4][0], ns0, 0, 0, 0);
      acc[5] = __builtin_amdgcn_mfma_f32_16x16x32_f16(af0, wf[5][0], ns1, 0, 0, 0);
    }
#pragma unroll
    for (int ks = 1; ks < 6; ks++) {
      const f16x8 af = *(const f16x8*)&hrd[ks * 32];
#pragma unroll
      for (int i = 0; i < 6; i++)
        acc[i] = __builtin_amdgcn_mfma_f32_16x16x32_f16(af, wf[i][ks], acc[i], 0, 0, 0);
    }
#pragma unroll
    for (int j = 0; j < 2; j++) {
      const f16x8 af = *(const f16x8*)&hrd[(6 + j) * 32];
#pragma unroll
      for (int i = 0; i < 6; i++) {
        const f16x8 bf = *(const f16x8*)&wrd[(i * 2 + j) * 512];
        acc[i] = __builtin_amdgcn_mfma_f32_16x16x32_f16(af, bf, acc[i], 0, 0, 0);
      }
    }
    __builtin_amdgcn_s_setprio(0);

    // phase B: per-r conditional gate blocks (execz-skipped once block dead)
#pragma unroll
    for (int r = 0; r < 4; r++) {
      const uint32_t sc = stcur[r], sn = stn[r];
      f16 hv0 = (f16)0.f, hv1 = (f16)0.f;
      if (sc & 0x80000000u) {
        const bool freshc = (sc & 0x40000000u) != 0;
        const uint32_t tb = sc & 0x1FFFFu;
        const bool keep = (sn & 0xC0000000u) == 0x80000000u;
        H2U u0; u0.u = rzC[r * 2];
        const float rr0 = sigm((float)u0.h[0] + acc[0][r]);
        const float zz0 = sigm((float)u0.h[1] + acc[2][r]);
        const float nn0 = tanh_f((float)gnC[r * 2] + rr0 * acc[4][r]);
        const float hpv0 = freshc ? 0.f : hp[r][0];
        const float ho0 = nn0 + zz0 * (hpv0 - nn0);
        hp[r][0] = ho0;
        H2U u1; u1.u = rzC[r * 2 + 1];
        const float rr1 = sigm((float)u1.h[0] + acc[1][r]);
        const float zz1 = sigm((float)u1.h[1] + acc[3][r]);
        const float nn1 = tanh_f((float)gnC[r * 2 + 1] + rr1 * acc[5][r]);
        const float hpv1 = freshc ? 0.f : hp[r][1];
        const float ho1 = nn1 + zz1 * (hpv1 - nn1);
        hp[r][1] = ho1;
        xgi[tb * 256u + colA] = (f16)ho0;
        xgi[tb * 256u + colB] = (f16)ho1;
        if (keep) { hv0 = (f16)ho0; hv1 = (f16)ho1; }
      }
      h_l[hc ^ 1][g4 + r][colA] = hv0;
      h_l[hc ^ 1][g4 + r][colB] = hv1;
    }
#pragma unroll
    for (int i = 0; i < 8; i++) { rzC[i] = rzN[i]; gnC[i] = gnN[i]; }
#pragma unroll
    for (int r = 0; r < 4; r++) stcur[r] = stn[r];

    __builtin_amdgcn_sched_barrier(0);
    asm volatile("s_waitcnt lgkmcnt(0)" ::: "memory");
    __builtin_amdgcn_s_barrier();
    __builtin_amdgcn_sched_barrier(0);

    hc ^= 1;
    const int tr = i0; i0 = i1; i1 = i2; i2 = tr;
  }
}

// ---------------------------------------------------------------------------
// K4: heads. M-tile 128, N=32 (16 pol + 1 val + pad), grid 1024, block 512.
// ---------------------------------------------------------------------------
__global__ __launch_bounds__(512) void k_heads(const f16* __restrict__ outs,
                                               const f16* __restrict__ headW_h,
                                               const float* __restrict__ pol_b,
                                               const float* __restrict__ val_b,
                                               float* __restrict__ out) {
  __shared__ f16 lA[128 * 256];
  __shared__ f16 lB[32 * 256];
  const int tid = threadIdx.x, lane = tid & 63, w = tid >> 6;
  const int m0 = blockIdx.x * 128;
#pragma unroll
  for (int i = 0; i < 8; i++) {
    int c = tid + i * 512;
    int r = c >> 5, o = (c & 31) * 8;
    f16x8 v = *(const f16x8*)(outs + (size_t)(m0 + r) * H_DIM + o);
    uint32_t off = ((uint32_t)(r * 512 + o * 2)) ^ (((uint32_t)(r & 7)) << 4);
    *(f16x8*)((char*)lA + off) = v;
  }
#pragma unroll
  for (int i = 0; i < 2; i++) {
    int c = tid + i * 512;
    int r = c >> 5, o = (c & 31) * 8;
    f16x8 v = *(const f16x8*)(headW_h + (size_t)r * H_DIM + o);
    uint32_t off = ((uint32_t)(r * 512 + o * 2)) ^ (((uint32_t)(r & 7)) << 4);
    *(f16x8*)((char*)lB + off) = v;
  }
  __syncthreads();
  f32x4 acc[2];
  acc[0] = fz4(); acc[1] = fz4();
#pragma unroll
  for (int ks = 0; ks < 8; ks++) {
    const int ar = w * 16 + (lane & 15);
    const int kofs = (ks * 32 + ((lane >> 4) << 3)) * 2;
    uint32_t aoff = ((uint32_t)(ar * 512 + kofs)) ^ (((uint32_t)(ar & 7)) << 4);
    f16x8 af = *(const f16x8*)((char*)lA + aoff);
#pragma unroll
    for (int nt = 0; nt < 2; nt++) {
      const int br = nt * 16 + (lane & 15);
      uint32_t boff = ((uint32_t)(br * 512 + kofs)) ^ (((uint32_t)(br & 7)) << 4);
      f16x8 bfr = *(const f16x8*)((char*)lB + boff);
      acc[nt] = __builtin_amdgcn_mfma_f32_16x16x32_f16(af, bfr, acc[nt], 0, 0, 0);
    }
  }
  const int n = lane & 15;
  const float pb = pol_b[n];
  const float vb = val_b[0];
#pragma unroll
  for (int r = 0; r < 4; r++) {
    const int mrow = m0 + w * 16 + ((lane >> 4) << 2) + r;
    out[(size_t)mrow * 16 + n] = acc[0][r] + pb;
    if (n == 0) out[(size_t)TB * 16 + mrow] = acc[1][r] + vb;
  }
}

// ---------------------------------------------------------------------------
// Workspace layout (~193.0 MiB total):
//   [0,128Mi)          gi_rz f16 [TB][256][2] (r,z interleaved; u32 cells)
//   [128Mi,192Mi)      xgi  f16 [TB][256]  (gi_n -> outs, race-free)
//   [192Mi,+464KB)     encW_h | Wih_h | headW_h
//   [+464KB,+976KB)    seg u32[131072] | meta u32[1]
// ---------------------------------------------------------------------------
extern "C" void kernel_launch(void* const* d_in, const int* in_sizes, int n_in,
                              void* d_out, int out_size, void* d_ws, size_t ws_size,
                              hipStream_t stream) {
  (void)in_sizes; (void)n_in; (void)out_size; (void)ws_size;
  const float* obs   = (const float*)d_in[0];
  const float* done  = (const float*)d_in[1];
  const float* encW  = (const float*)d_in[2];
  const float* enc_b = (const float*)d_in[3];
  const float* Wih   = (const float*)d_in[4];
  const float* Whh   = (const float*)d_in[5];
  const float* b_ih  = (const float*)d_in[6];
  const float* b_hh  = (const float*)d_in[7];
  const float* polW  = (const float*)d_in[8];
  const float* pol_b = (const float*)d_in[9];
  const float* valW  = (const float*)d_in[10];
  const float* val_b = (const float*)d_in[11];

  char* ws = (char*)d_ws;
  f16* gi_rz   = (f16*)ws;
  f16* xgi     = (f16*)(ws + (size_t)134217728);
  f16* encW_h  = (f16*)(ws + (size_t)201326592);
  f16* Wih_h   = encW_h + 32768;
  f16* headW_h = Wih_h + 196608;
  uint32_t* seg  = (uint32_t*)(ws + (size_t)201801728);
  uint32_t* meta = (uint32_t*)(ws + (size_t)202326016);
  float* outp  = (float*)d_out;

  k_prep<<<dim3(928), dim3(256), 0, stream>>>(encW, Wih, polW, valW, encW_h, Wih_h, headW_h);
  k_sched<<<dim3(1), dim3(1024), 0, stream>>>(done, seg, meta);
  k_encgi<<<dim3(2048), dim3(512), 0, stream>>>(obs, encW_h, enc_b, Wih_h, b_ih, b_hh,
                                                (uint32_t*)gi_rz, xgi);
  k_scan<<<dim3(256), dim3(512), 0, stream>>>(Whh, b_hh, seg, meta,
                                              (const uint32_t*)gi_rz, xgi);
  k_heads<<<dim3(1024), dim3(512), 0, stream>>>(xgi, headW_h, pol_b, val_b, outp);
}